// Round 5
// baseline (338.990 us; speedup 1.0000x reference)
//
#include <hip/hip_runtime.h>
#include <cstddef>
#include <cstdint>

// ST-GCN block, single fused kernel.
//  Stage 1: D[pos][os] = X^T W^T + cb, pos = m*32+v (v pad 25->32), per wave:
//           os = s*64 + wv*16 + l15 for s=0..2  -> wave-PRIVATE Ys region.
//  Stage 2: Z[o][w] = sum_s Y_s[o][v] PA_s[v][w] -- A-frags read back from the
//           wave's own Ys (no cross-wave dep => NO barrier between stages).
//  One inline-asm barrier per t (lgkmcnt only -- no vmcnt(0) store/prefetch
//  drain), depth-2 global prefetch kept in flight across it.
#define N_  32
#define C_  64
#define T_  300
#define V_  25
#define M_  2
#define S_  3
#define O_  64
#define TB  6
#define NT_BLK (T_/TB)       // 50
#define CTVM (C_*T_*V_*M_)   // 960000
#define TVM  (T_*V_*M_)      // 15000
#define VM   (V_*M_)         // 50
#define XPITCH 72            // shorts: 144B rows (16B-aligned for b128)
#define YPITCH 72

typedef short  short8  __attribute__((ext_vector_type(8)));
typedef float  float4_ __attribute__((ext_vector_type(4)));

__device__ __forceinline__ short f2bf(float f) {   // fp32 -> bf16 RNE
    uint32_t u = __float_as_uint(f);
    u += 0x7FFFu + ((u >> 16) & 1u);
    return (short)(u >> 16);
}
__device__ __forceinline__ unsigned pk2bf(float a, float b) {  // lo=a, hi=b
    return (uint32_t)(uint16_t)f2bf(a) | ((uint32_t)(uint16_t)f2bf(b) << 16);
}
__device__ __forceinline__ void barrier_lgkm() {   // barrier WITHOUT vmcnt drain
    asm volatile("s_waitcnt lgkmcnt(0)\n\ts_barrier" ::: "memory");
}
__device__ __forceinline__ void wait_lgkm() {
    asm volatile("s_waitcnt lgkmcnt(0)" ::: "memory");
}

__global__ __launch_bounds__(256, 3)
void stgcn_fused(const float* __restrict__ x,  const float* __restrict__ PA,
                 const float* __restrict__ Wc, const float* __restrict__ cb,
                 const float* __restrict__ g,  const float* __restrict__ bb,
                 const float* __restrict__ mn, const float* __restrict__ vr,
                 float* __restrict__ out)
{
    __shared__ short Xb[2][64 * XPITCH];     // 18.0 KB double-buffered X tile
    __shared__ short Ysw[4 * 48 * YPITCH];   // 27.0 KB, wave-private quarters
    __shared__ float sclS[O_], sftS[O_];

    const int tid  = threadIdx.x;
    const int wv   = tid >> 6;
    const int lane = tid & 63;
    const int quad = lane >> 4;
    const int l15  = lane & 15;
    const int ybase = wv * 48 * YPITCH;

    const int n  = blockIdx.x / NT_BLK;
    const int t0 = (blockIdx.x % NT_BLK) * TB;
    const size_t xbase = (size_t)n * CTVM;

    // ---- issue x loads for t0 and t0+1 immediately (longest latency) ----
    float2 P0[4], P1[4];            // t0
    float2 Rx[2][4], Ry[2][4];      // regsets: slot (i&1) holds t0+i+1
    {
        const float* xt = x + xbase + (size_t)t0 * VM;
        #pragma unroll
        for (int k = 0; k < 4; ++k) {
            const int p = tid + k * 256;
            if (p < 800) {
                const int v = p % 25, cp = p / 25;
                P0[k] = *(const float2*)(xt + (size_t)(2 * cp)     * TVM + v * 2);
                P1[k] = *(const float2*)(xt + (size_t)(2 * cp + 1) * TVM + v * 2);
                Rx[0][k] = *(const float2*)(xt + (size_t)(2 * cp)     * TVM + VM + v * 2);
                Ry[0][k] = *(const float2*)(xt + (size_t)(2 * cp + 1) * TVM + VM + v * 2);
            }
        }
    }

    // ---- one-time fragment construction from fp32 sources (L2/L3-hot) ----
    short8 aW[3][2];   // stage-1 B-operand: B[k=c][n=os], os = s*64+wv*16+l15
    #pragma unroll
    for (int s = 0; s < 3; ++s)
        #pragma unroll
        for (int ks = 0; ks < 2; ++ks) {
            const float* wr = Wc + (size_t)(s * 64 + wv * 16 + l15) * C_ + ks * 32 + quad * 8;
            const float4 wa = *(const float4*)wr;
            const float4 wb = *(const float4*)(wr + 4);
            union { short8 s8; unsigned u[4]; } r;
            r.u[0] = pk2bf(wa.x, wa.y); r.u[1] = pk2bf(wa.z, wa.w);
            r.u[2] = pk2bf(wb.x, wb.y); r.u[3] = pk2bf(wb.z, wb.w);
            aW[s][ks] = r.s8;
        }

    short8 bP[3][2];   // stage-2 B-operand: B[k=v=quad*8+j][n=w=wt*16+l15], pads 0
    #pragma unroll
    for (int s = 0; s < 3; ++s)
        #pragma unroll
        for (int wt = 0; wt < 2; ++wt) {
            const int w = wt * 16 + l15;
            float pv[8];
            #pragma unroll
            for (int j = 0; j < 8; ++j) {
                const int v = quad * 8 + j;
                pv[j] = (w < V_ && v < V_) ? PA[s * V_ * V_ + v * V_ + w] : 0.0f;
            }
            union { short8 s8; unsigned u[4]; } r;
            r.u[0] = pk2bf(pv[0], pv[1]); r.u[1] = pk2bf(pv[2], pv[3]);
            r.u[2] = pk2bf(pv[4], pv[5]); r.u[3] = pk2bf(pv[6], pv[7]);
            bP[s][wt] = r.s8;
        }

    float cbw[3];      // stage-1 bias per D-column (os)
    #pragma unroll
    for (int s = 0; s < 3; ++s) cbw[s] = cb[s * 64 + wv * 16 + l15];

    if (tid < O_) {    // BN fold
        const float sc = g[tid] * rsqrtf(vr[tid] + 1e-5f);
        sclS[tid] = sc;
        sftS[tid] = bb[tid] - mn[tid] * sc;
    }

    // zero v-pad rows (pos 25..31, 57..63) of both X buffers, once
    for (int i = tid; i < 2 * 14 * XPITCH; i += 256) {
        const int bf = i / (14 * XPITCH);
        const int r  = i - bf * (14 * XPITCH);
        const int pr = r / XPITCH, cc = r - pr * XPITCH;
        const int pos = (pr < 7) ? (25 + pr) : (50 + pr);
        Xb[bf][pos * XPITCH + cc] = 0;
    }

    // convert t0 into Xb[0]
    #pragma unroll
    for (int k = 0; k < 4; ++k) {
        const int p = tid + k * 256;
        if (p < 800) {
            const int v = p % 25, cp = p / 25;
            ((unsigned*)Xb[0])[v * 36 + cp]        = pk2bf(P0[k].x, P1[k].x);  // m=0
            ((unsigned*)Xb[0])[(32 + v) * 36 + cp] = pk2bf(P0[k].y, P1[k].y);  // m=1
        }
    }
    barrier_lgkm();

    // per-lane BN constants for o = wv*16 + quad*4 + r
    const float4 sclr = *(const float4*)&sclS[wv * 16 + quad * 4];
    const float4 sftr = *(const float4*)&sftS[wv * 16 + quad * 4];
    const float sclA[4] = { sclr.x, sclr.y, sclr.z, sclr.w };
    const float sftA[4] = { sftr.x, sftr.y, sftr.z, sftr.w };

    for (int i = 0; i < TB; ++i) {
        const int t   = t0 + i;
        const int cur = i & 1, nxt = cur ^ 1;

        // ---- issue prefetch for t+2 (lands ~2 iterations later) ----
        if (i + 2 < TB) {
            const float* xt = x + xbase + (size_t)(t + 2) * VM;
            const int sl = (i + 1) & 1;
            #pragma unroll
            for (int k = 0; k < 4; ++k) {
                const int p = tid + k * 256;
                if (p < 800) {
                    const int v = p % 25, cp = p / 25;
                    Rx[sl][k] = *(const float2*)(xt + (size_t)(2 * cp)     * TVM + v * 2);
                    Ry[sl][k] = *(const float2*)(xt + (size_t)(2 * cp + 1) * TVM + v * 2);
                }
            }
        }

        // ---- stage 1: 12 16x16 tiles -> wave-private Ys ----
        const short* Xc = Xb[cur];
        short8 bX[4][2];
        #pragma unroll
        for (int nt = 0; nt < 4; ++nt)
            #pragma unroll
            for (int ks = 0; ks < 2; ++ks)
                bX[nt][ks] = *(const short8*)(Xc + (nt * 16 + l15) * XPITCH + ks * 32 + quad * 8);

        #pragma unroll
        for (int s = 0; s < 3; ++s) {
            #pragma unroll
            for (int nt = 0; nt < 4; ++nt) {
                float4_ acc = { cbw[s], cbw[s], cbw[s], cbw[s] };
                acc = __builtin_amdgcn_mfma_f32_16x16x32_bf16(bX[nt][0], aW[s][0], acc, 0, 0, 0);
                acc = __builtin_amdgcn_mfma_f32_16x16x32_bf16(bX[nt][1], aW[s][1], acc, 0, 0, 0);
                // D: row=pos=nt*16+quad*4+r, col=os(l15). Private row (s*16+l15), col pos.
                *(uint2*)(Ysw + ybase + (s * 16 + l15) * YPITCH + nt * 16 + quad * 4) =
                    make_uint2(pk2bf(acc[0], acc[1]), pk2bf(acc[2], acc[3]));
            }
        }
        wait_lgkm();   // own-wave Ys writes -> readable (no barrier needed)

        // ---- stage 2: Z[o][w] = sum_s Y_s[o][v] PA_s[v][w] ----
        float4_ z[2][2];
        #pragma unroll
        for (int m = 0; m < 2; ++m)
            #pragma unroll
            for (int wt = 0; wt < 2; ++wt)
                { z[m][wt][0]=0.f; z[m][wt][1]=0.f; z[m][wt][2]=0.f; z[m][wt][3]=0.f; }
        #pragma unroll
        for (int m = 0; m < 2; ++m) {
            #pragma unroll
            for (int s = 0; s < 3; ++s) {
                const short8 aY = *(const short8*)(Ysw + ybase + (s * 16 + l15) * YPITCH + m * 32 + quad * 8);
                z[m][0] = __builtin_amdgcn_mfma_f32_16x16x32_bf16(aY, bP[s][0], z[m][0], 0, 0, 0);
                z[m][1] = __builtin_amdgcn_mfma_f32_16x16x32_bf16(aY, bP[s][1], z[m][1], 0, 0, 0);
            }
        }

        // ---- epilogue: BN+relu+residual+relu, m-paired float2 stores ----
        #pragma unroll
        for (int wt = 0; wt < 2; ++wt) {
            const int wc = wt * 16 + l15;
            if (wc < V_) {
                #pragma unroll
                for (int r = 0; r < 4; ++r) {
                    const int o = wv * 16 + quad * 4 + r;
                    const float r0 = __uint_as_float(((unsigned)(unsigned short)Xc[(wc)      * XPITCH + o]) << 16);
                    const float r1 = __uint_as_float(((unsigned)(unsigned short)Xc[(32 + wc) * XPITCH + o]) << 16);
                    float q0 = fmaf(z[0][wt][r], sclA[r], sftA[r]);
                    float q1 = fmaf(z[1][wt][r], sclA[r], sftA[r]);
                    q0 = fmaxf(fmaxf(q0, 0.0f) + r0, 0.0f);
                    q1 = fmaxf(fmaxf(q1, 0.0f) + r1, 0.0f);
                    *(float2*)(out + xbase + (size_t)o * TVM + (size_t)t * VM + wc * 2) =
                        make_float2(q0, q1);
                }
            }
        }

        // ---- convert regset (t+1) into Xb[nxt] ----
        if (i + 1 < TB) {
            const int sl = i & 1;
            #pragma unroll
            for (int k = 0; k < 4; ++k) {
                const int p = tid + k * 256;
                if (p < 800) {
                    const int v = p % 25, cp = p / 25;
                    ((unsigned*)Xb[nxt])[v * 36 + cp]        = pk2bf(Rx[sl][k].x, Ry[sl][k].x);
                    ((unsigned*)Xb[nxt])[(32 + v) * 36 + cp] = pk2bf(Rx[sl][k].y, Ry[sl][k].y);
                }
            }
        }
        barrier_lgkm();   // lgkm only: stores + t+2 loads stay in flight
    }
}

extern "C" void kernel_launch(void* const* d_in, const int* in_sizes, int n_in,
                              void* d_out, int out_size, void* d_ws, size_t ws_size,
                              hipStream_t stream)
{
    const float* x    = (const float*)d_in[0];  // (32,64,300,25,2)
    const float* PA   = (const float*)d_in[1];  // (3,25,25)
    const float* Wc   = (const float*)d_in[2];  // (192,64)
    const float* cb   = (const float*)d_in[3];  // (192,)
    const float* bn_g = (const float*)d_in[4];
    const float* bn_b = (const float*)d_in[5];
    const float* bn_m = (const float*)d_in[6];
    const float* bn_v = (const float*)d_in[7];
    float* out = (float*)d_out;

    stgcn_fused<<<N_ * NT_BLK, 256, 0, stream>>>(x, PA, Wc, cb, bn_g, bn_b, bn_m, bn_v, out);
}

// Round 6
// 324.735 us; speedup vs baseline: 1.0439x; 1.0439x over previous
//
#include <hip/hip_runtime.h>
#include <cstddef>
#include <cstdint>

// ST-GCN block. Round 6: round-4 structure + wave-private Ys (no cross-wave
// stage1->stage2 dep) + lgkm-only barriers (stores/prefetch never drained at
// barriers) + single Xb (LDS 36.9KB -> 4 blocks/CU).
//  Stage 1: D[pos][os] = X^T W^T + cb, pos=m*32+v (v pad 25->32); wave wv owns
//           os = s*64 + wv*16 + l15, s=0..2 -> its private Ysw quarter.
//  Stage 2: Z[o][w] = sum_s Y_s[o][v] PA_s[v][w], K=32 (PA pads zero), o in
//           wv's 16-row range, both m, from own Ysw only.
#define N_  32
#define C_  64
#define T_  300
#define V_  25
#define M_  2
#define S_  3
#define O_  64
#define OS_ 192
#define TB  6
#define NT_BLK (T_/TB)       // 50
#define CTVM (C_*T_*V_*M_)   // 960000
#define TVM  (T_*V_*M_)      // 15000
#define VM   (V_*M_)         // 50
#define XPITCH 72            // shorts: 144B rows, 16B-aligned b128 reads
#define YPITCH 72

typedef short  short8  __attribute__((ext_vector_type(8)));
typedef float  float4_ __attribute__((ext_vector_type(4)));

__device__ __forceinline__ short f2bf(float f) {   // fp32 -> bf16 RNE
    uint32_t u = __float_as_uint(f);
    u += 0x7FFFu + ((u >> 16) & 1u);
    return (short)(u >> 16);
}
__device__ __forceinline__ unsigned pk2bf(float a, float b) {  // lo=a, hi=b
    return (uint32_t)(uint16_t)f2bf(a) | ((uint32_t)(uint16_t)f2bf(b) << 16);
}
__device__ __forceinline__ void barrier_lgkm() {   // barrier WITHOUT vmcnt drain
    asm volatile("s_waitcnt lgkmcnt(0)\n\ts_barrier" ::: "memory");
}
__device__ __forceinline__ float bf2f(unsigned bits16) {
    return __uint_as_float(bits16 << 16);
}

// prep: W -> bf16 [os][c]; PA -> bf16 transposed+padded [s][w32][v32]; BN fold.
__global__ void stgcn_prep(const float* __restrict__ Wc, const float* __restrict__ PA,
                           const float* __restrict__ g,  const float* __restrict__ b,
                           const float* __restrict__ mn, const float* __restrict__ vr,
                           short* __restrict__ Wb, short* __restrict__ PAb,
                           float* __restrict__ scl, float* __restrict__ sft)
{
    const int i = blockIdx.x * 256 + threadIdx.x;
    if (i < OS_ * C_) Wb[i] = f2bf(Wc[i]);
    const int r = i - OS_ * C_;
    if (r >= 0 && r < S_ * 32 * 32) {
        const int s = r >> 10, rem = r & 1023, wp = rem >> 5, vp = rem & 31;
        const float val = (wp < V_ && vp < V_) ? PA[s * V_ * V_ + vp * V_ + wp] : 0.0f;
        PAb[r] = f2bf(val);
    }
    const int q = r - S_ * 32 * 32;
    if (q >= 0 && q < O_) {
        const float sc = g[q] * rsqrtf(vr[q] + 1e-5f);
        scl[q] = sc;
        sft[q] = b[q] - mn[q] * sc;
    }
}

__global__ __launch_bounds__(256, 4)
void stgcn_main(const float* __restrict__ x, const float* __restrict__ cb,
                const short* __restrict__ Wb, const short* __restrict__ PAb,
                const float* __restrict__ sclg, const float* __restrict__ sftg,
                float* __restrict__ out)
{
    __shared__ short Xb[64 * XPITCH];        //  9.2 KB, single buffer
    __shared__ short Ysw[4 * 48 * YPITCH];   // 27.6 KB, wave-private quarters

    const int tid  = threadIdx.x;
    const int wv   = tid >> 6;
    const int lane = tid & 63;
    const int quad = lane >> 4;
    const int l15  = lane & 15;
    const int ybase = wv * 48 * YPITCH;

    const int n  = blockIdx.x / NT_BLK;
    const int t0 = (blockIdx.x % NT_BLK) * TB;
    const size_t xbase = (size_t)n * CTVM;

    // ---- wave-constant fragments (from prep ws, L2-hot bf16) ----
    short8 aW[3][2];   // stage-1 B-operand: B[k=c][n=os], os = s*64+wv*16+l15
    #pragma unroll
    for (int s = 0; s < 3; ++s)
        #pragma unroll
        for (int ks = 0; ks < 2; ++ks)
            aW[s][ks] = *(const short8*)(Wb + (s * 64 + wv * 16 + l15) * C_ + ks * 32 + quad * 8);

    short8 bP[3][2];   // stage-2 B-operand: B[k=v][n=w=wt*16+l15]
    #pragma unroll
    for (int s = 0; s < 3; ++s)
        #pragma unroll
        for (int wt = 0; wt < 2; ++wt)
            bP[s][wt] = *(const short8*)(PAb + s * 1024 + (wt * 16 + l15) * 32 + quad * 8);

    float cbw[3];      // stage-1 bias per D-column (os)
    #pragma unroll
    for (int s = 0; s < 3; ++s) cbw[s] = cb[s * 64 + wv * 16 + l15];

    // per-lane BN constants for o = wv*16 + quad*4 + r
    const float4 sclr = *(const float4*)&sclg[wv * 16 + quad * 4];
    const float4 sftr = *(const float4*)&sftg[wv * 16 + quad * 4];
    const float sclA[4] = { sclr.x, sclr.y, sclr.z, sclr.w };
    const float sftA[4] = { sftr.x, sftr.y, sftr.z, sftr.w };

    // zero v-pad rows (pos 25..31, 57..63) once
    for (int i = tid; i < 14 * XPITCH; i += 256) {
        const int pr = i / XPITCH, cc = i - pr * XPITCH;
        const int pos = (pr < 7) ? (25 + pr) : (50 + pr);
        Xb[pos * XPITCH + cc] = 0;
    }

    // ---- prologue: stage t0 ----
    {
        const float* xt = x + xbase + (size_t)t0 * VM;
        #pragma unroll
        for (int k = 0; k < 4; ++k) {
            const int p = tid + k * 256;           // 800 (cpair, v) pairs
            if (p < 800) {
                const int v = p % 25, cp = p / 25;
                const float2 f0 = *(const float2*)(xt + (size_t)(2 * cp)     * TVM + v * 2);
                const float2 f1 = *(const float2*)(xt + (size_t)(2 * cp + 1) * TVM + v * 2);
                ((unsigned*)Xb)[v * 36 + cp]        = pk2bf(f0.x, f1.x);  // m=0
                ((unsigned*)Xb)[(32 + v) * 36 + cp] = pk2bf(f0.y, f1.y);  // m=1
            }
        }
    }

    for (int i = 0; i < TB; ++i) {
        const int t = t0 + i;
        barrier_lgkm();   // B0: Xb(t) visible to all waves (lgkm only)

        // ---- issue global prefetch for t+1 (in flight across both barriers) ----
        float2 Rx[4], Ry[4];
        const bool pf = (i + 1 < TB);
        if (pf) {
            const float* xt = x + xbase + (size_t)(t + 1) * VM;
            #pragma unroll
            for (int k = 0; k < 4; ++k) {
                const int p = tid + k * 256;
                if (p < 800) {
                    const int v = p % 25, cp = p / 25;
                    Rx[k] = *(const float2*)(xt + (size_t)(2 * cp)     * TVM + v * 2);
                    Ry[k] = *(const float2*)(xt + (size_t)(2 * cp + 1) * TVM + v * 2);
                }
            }
        }

        // ---- residual pre-read (before B1; Xb(t) rows, ds_read_b64) ----
        uint2 resp[2][2];   // [m][wt]: 4 packed bf16 for r=0..3 at o=wv*16+quad*4+r
        #pragma unroll
        for (int m = 0; m < 2; ++m)
            #pragma unroll
            for (int wt = 0; wt < 2; ++wt)
                resp[m][wt] = *(const uint2*)(Xb + (m * 32 + wt * 16 + l15) * XPITCH
                                                 + wv * 16 + quad * 4);

        // ---- stage 1: per-nt fragments (small live set), private Ys writes ----
        #pragma unroll
        for (int nt = 0; nt < 4; ++nt) {
            const short8 b0 = *(const short8*)(Xb + (nt * 16 + l15) * XPITCH + quad * 8);
            const short8 b1 = *(const short8*)(Xb + (nt * 16 + l15) * XPITCH + 32 + quad * 8);
            #pragma unroll
            for (int s = 0; s < 3; ++s) {
                float4_ acc = { cbw[s], cbw[s], cbw[s], cbw[s] };
                acc = __builtin_amdgcn_mfma_f32_16x16x32_bf16(b0, aW[s][0], acc, 0, 0, 0);
                acc = __builtin_amdgcn_mfma_f32_16x16x32_bf16(b1, aW[s][1], acc, 0, 0, 0);
                // D: row=pos=nt*16+quad*4+r, col=os(l15) -> private row (s*16+l15)
                *(uint2*)(Ysw + ybase + (s * 16 + l15) * YPITCH + nt * 16 + quad * 4) =
                    make_uint2(pk2bf(acc[0], acc[1]), pk2bf(acc[2], acc[3]));
            }
        }
        barrier_lgkm();   // B1: all waves' Xb(t) reads done + own Ys writes drained

        // ---- stage 2: Z[o][w] = sum_s Y_s[o][v] PA_s[v][w] ----
        float4_ z[2][2];
        #pragma unroll
        for (int m = 0; m < 2; ++m)
            #pragma unroll
            for (int wt = 0; wt < 2; ++wt)
                { z[m][wt][0]=0.f; z[m][wt][1]=0.f; z[m][wt][2]=0.f; z[m][wt][3]=0.f; }
        #pragma unroll
        for (int m = 0; m < 2; ++m) {
            #pragma unroll
            for (int s = 0; s < 3; ++s) {
                const short8 aY = *(const short8*)(Ysw + ybase + (s * 16 + l15) * YPITCH
                                                       + m * 32 + quad * 8);
                z[m][0] = __builtin_amdgcn_mfma_f32_16x16x32_bf16(aY, bP[s][0], z[m][0], 0, 0, 0);
                z[m][1] = __builtin_amdgcn_mfma_f32_16x16x32_bf16(aY, bP[s][1], z[m][1], 0, 0, 0);
            }
        }

        // ---- epilogue: BN+relu+residual+relu, m-paired float2 stores ----
        #pragma unroll
        for (int wt = 0; wt < 2; ++wt) {
            const int wc = wt * 16 + l15;
            if (wc < V_) {
                #pragma unroll
                for (int r = 0; r < 4; ++r) {
                    const int o = wv * 16 + quad * 4 + r;
                    const unsigned pr0 = (r < 2) ? resp[0][wt].x : resp[0][wt].y;
                    const unsigned pr1 = (r < 2) ? resp[1][wt].x : resp[1][wt].y;
                    const float r0 = bf2f((r & 1) ? (pr0 >> 16) : (pr0 & 0xFFFFu));
                    const float r1 = bf2f((r & 1) ? (pr1 >> 16) : (pr1 & 0xFFFFu));
                    float q0 = fmaf(z[0][wt][r], sclA[r], sftA[r]);
                    float q1 = fmaf(z[1][wt][r], sclA[r], sftA[r]);
                    q0 = fmaxf(fmaxf(q0, 0.0f) + r0, 0.0f);
                    q1 = fmaxf(fmaxf(q1, 0.0f) + r1, 0.0f);
                    *(float2*)(out + xbase + (size_t)o * TVM + (size_t)t * VM + wc * 2) =
                        make_float2(q0, q1);
                }
            }
        }

        // ---- convert prefetch into Xb (all waves past B1 -> reads done) ----
        if (pf) {
            #pragma unroll
            for (int k = 0; k < 4; ++k) {
                const int p = tid + k * 256;
                if (p < 800) {
                    const int v = p % 25, cp = p / 25;
                    ((unsigned*)Xb)[v * 36 + cp]        = pk2bf(Rx[k].x, Ry[k].x);
                    ((unsigned*)Xb)[(32 + v) * 36 + cp] = pk2bf(Rx[k].y, Ry[k].y);
                }
            }
        }
    }
}

extern "C" void kernel_launch(void* const* d_in, const int* in_sizes, int n_in,
                              void* d_out, int out_size, void* d_ws, size_t ws_size,
                              hipStream_t stream)
{
    const float* x    = (const float*)d_in[0];  // (32,64,300,25,2)
    const float* PA   = (const float*)d_in[1];  // (3,25,25)
    const float* Wc   = (const float*)d_in[2];  // (192,64)
    const float* cb   = (const float*)d_in[3];  // (192,)
    const float* bn_g = (const float*)d_in[4];
    const float* bn_b = (const float*)d_in[5];
    const float* bn_m = (const float*)d_in[6];
    const float* bn_v = (const float*)d_in[7];
    float* out = (float*)d_out;

    char* ws = (char*)d_ws;
    short* Wb  = (short*)ws;                    // 12288 bf16
    short* PAb = (short*)(ws + 24576);          //  3072 bf16
    float* scl = (float*)(ws + 30720);          //    64 f32
    float* sft = (float*)(ws + 30976);          //    64 f32

    stgcn_prep<<<61, 256, 0, stream>>>(Wc, PA, bn_g, bn_b, bn_m, bn_v, Wb, PAb, scl, sft);
    stgcn_main<<<N_ * NT_BLK, 256, 0, stream>>>(x, cb, Wb, PAb, scl, sft, out);
}